// Round 13
// baseline (117.456 us; speedup 1.0000x reference)
//
#include <hip/hip_runtime.h>
#include <hip/hip_bf16.h>
#include <stdint.h>

// ---------------------------------------------------------------------------
// Decoder_10110353014984: LIF multistep (T=4) + linear head
//   x: [4,64,196,512] f32, W: [1000,512] f32, b: [1000] f32
//   y: [4,64,196,1000] f32
// R13 = R12 with GEMM wave-tile reuse increased: block 256x128, 4 waves
//   (2Mx2N), wave tile 128x64 -> LDS bytes/MAC x0.75 (LDS-read BW is the
//   measured structural bottleneck: ~1000cyc LDS vs ~620cyc MFMA per CU
//   round in R12's 64x64-wave structure). LDS 48KB -> 3 blocks/CU;
//   __launch_bounds__(256,3); A-frags streamed singly to stay <=170 VGPR.
//   Grid 1600 (32 dead blocks exit early); XCD grouping preserved.
//   lifw kernel identical to R12 (measured at HBM floor).
// ---------------------------------------------------------------------------

typedef __attribute__((ext_vector_type(8))) short bf16x8;
typedef __attribute__((ext_vector_type(4))) float f32x4;

#define AS1(p) ((const __attribute__((address_space(1))) void*)(p))
#define AS3(p) ((__attribute__((address_space(3))) void*)(p))

static constexpr int     T_STEPS = 4;
static constexpr int64_t ESP     = 6422528;   // B*N*D = 64*196*512
static constexpr int     K_DIM   = 512;
static constexpr int     C_DIM   = 1000;
static constexpr int64_t M_ROWS  = 50176;     // T*B*N

static constexpr int LIF_BLOCKS = 3136;       // 3136*256 thr * 2 quads = ESP/4
static constexpr int WCV_BLOCKS = 512;        // 512*256*4 elem = 1024*512

__device__ __forceinline__ unsigned short f2bf(float f) {
  unsigned int u = __float_as_uint(f);
  u += 0x7FFFu + ((u >> 16) & 1u);            // round-to-nearest-even
  return (unsigned short)(u >> 16);
}

// ---------------------------------------------------------------------------
// Kernel 1: LIF dynamics -> bf16 spikes + W f32->bf16 in trailing blocks.
// LIF bit-exact vs ref: v += (x-v)*0.5f (exact *0.5), spike iff v >= 1.0f,
// hard reset.
// ---------------------------------------------------------------------------
__global__ void lifw_kernel(const float* __restrict__ x,
                            unsigned short* __restrict__ S,
                            const float* __restrict__ W,
                            unsigned short* __restrict__ Wb) {
  const int b = blockIdx.x;
  if (b >= LIF_BLOCKS) {
    const int idx = (b - LIF_BLOCKS) * 256 + threadIdx.x;  // 0..131071
    const int64_t base = (int64_t)idx * 4;
    const int row = (int)(base >> 9);
    ushort4 o;
    if (row < C_DIM) {
      const float4 wv = *(const float4*)(W + base);
      o.x = f2bf(wv.x); o.y = f2bf(wv.y); o.z = f2bf(wv.z); o.w = f2bf(wv.w);
    } else {
      o.x = o.y = o.z = o.w = 0;
    }
    *(ushort4*)(Wb + base) = o;
    return;
  }
  const int64_t tb = (int64_t)b * 256 + threadIdx.x;
#pragma unroll
  for (int it = 0; it < 2; ++it) {
    const int64_t s0 = (tb + (int64_t)it * LIF_BLOCKS * 256) << 2;
    float v[4] = {0.f, 0.f, 0.f, 0.f};
#pragma unroll
    for (int t = 0; t < T_STEPS; ++t) {
      const float4 xt = *(const float4*)(x + (int64_t)t * ESP + s0);
      const float xa[4] = {xt.x, xt.y, xt.z, xt.w};
      ushort4 sp;
      unsigned short* spp = &sp.x;
#pragma unroll
      for (int j = 0; j < 4; ++j) {
        v[j] = v[j] + (xa[j] - v[j]) * 0.5f;   // charge
        const bool fire = (v[j] >= 1.0f);
        spp[j] = fire ? (unsigned short)0x3F80 : (unsigned short)0; // bf16 1/0
        if (fire) v[j] = 0.0f;                 // hard reset
      }
      *(ushort4*)(S + (int64_t)t * ESP + s0) = sp;
    }
  }
}

// ---------------------------------------------------------------------------
// Kernel 2: GEMM  Y[m,c] = sum_d S[m,d] * Wb[c,d] + b[c]
// Block 256x128, BK=64, 256 threads (4 waves 2Mx2N, wave tile 128x64),
// single-buffered 48KB LDS (A 32KB + B 16KB), m97 2-barrier K-loop,
// 3 blocks/CU. Grid 1600 = 8 XCDs x 200; per XCD 8 consecutive blocks =
// the 8 c-panels of one m-tile (A-tile 256KB L2-shared); mtile>=196 exits.
// Per wave per K-tile: 4 B-frag reads cached + 16 A-frag reads streamed,
// 64 MFMA -> LDS bytes/MAC 0.75x of the 64x64-wave structure.
// Epilogue: 4 slices of 64 rows staged in LDS (32KB obuf), streamed as
// full 128B lines, nontemporal.
// ---------------------------------------------------------------------------
__global__ __launch_bounds__(256, 3) void gemm_kernel(
    const unsigned short* __restrict__ S,
    const unsigned short* __restrict__ Wb,
    const float* __restrict__ bias,
    float* __restrict__ Y) {
  __shared__ __attribute__((aligned(16))) unsigned short As[256 * 64]; // 32KB
  __shared__ __attribute__((aligned(16))) unsigned short Bs[128 * 64]; // 16KB

  const int tid  = threadIdx.x;
  const int lane = tid & 63;
  const int wid  = tid >> 6;      // 0..3
  const int wm   = wid >> 1;      // 0..1  (M half: 128 rows)
  const int wn   = wid & 1;       // 0..1  (N half: 64 cols)

  // XCD grouping: xcd = bid&7 (round-robin dispatch); j = bid>>3 in 0..199.
  // mtile = (j>>3)*8 + xcd: per XCD, 8 consecutive j share one m-tile
  // (8 c-panels adjacent in time). mtile >= 196 -> dead block, exit.
  const int bid   = blockIdx.x;
  const int xcd   = bid & 7;
  const int j     = bid >> 3;
  const int mtile = (j >> 3) * 8 + xcd;
  const int ntile = j & 7;
  if (mtile >= 196) return;
  const int64_t row0 = (int64_t)mtile * 256;
  const int     c0   = ntile * 128;

  // staging: one issue = 256 thr x 16B = 4KB = 32 rows x 128B. LDS dest is
  // wave-uniform + lane*16 (linear); swizzle on the GLOBAL source column.
  const int srow = lane >> 3;                 // 0..7
  const int skb  = ((lane & 7) ^ srow) << 4;

  const char* Sg = (const char*)S;
  const char* Wg = (const char*)Wb;
  char* Ab = (char*)As;
  char* Bb = (char*)Bs;

  f32x4 acc[8][4] = {};

  const int lr = lane & 15;
  const int lk = (lane >> 4) * 16;

  for (int t = 0; t < 8; ++t) {            // 8 K-tiles of 64
    const int k0 = t * 64;
#pragma unroll
    for (int i = 0; i < 8; ++i) {          // A: 256 rows = 8 issues
      const int rr = i * 32 + wid * 8;
      __builtin_amdgcn_global_load_lds(
          AS1(Sg + ((row0 + rr + srow) * (int64_t)K_DIM + k0) * 2 + skb),
          AS3(Ab + rr * 128), 16, 0, 0);
    }
#pragma unroll
    for (int i = 0; i < 4; ++i) {          // B: 128 rows = 4 issues
      const int rr = i * 32 + wid * 8;
      __builtin_amdgcn_global_load_lds(
          AS1(Wg + (((int64_t)c0 + rr + srow) * K_DIM + k0) * 2 + skb),
          AS3(Bb + rr * 128), 16, 0, 0);
    }
    __syncthreads();                       // staging complete

#pragma unroll
    for (int half = 0; half < 2; ++half) { // kk slice of BK=64
      const int kb = half * 64 + lk;
      bf16x8 bfr[4];
#pragma unroll
      for (int nj = 0; nj < 4; ++nj) {
        const int r = wn * 64 + nj * 16 + lr;
        bfr[nj] = *(const bf16x8*)(Bb + r * 128 + (kb ^ ((r & 7) << 4)));
      }
      // A-frags streamed one at a time (VGPR cap 170 under (256,3));
      // compiler hoists loads as budget allows.
#pragma unroll
      for (int mi = 0; mi < 8; ++mi) {
        const int r = wm * 128 + mi * 16 + lr;
        const bf16x8 afr =
            *(const bf16x8*)(Ab + r * 128 + (kb ^ ((r & 7) << 4)));
#pragma unroll
        for (int nj = 0; nj < 4; ++nj)
          acc[mi][nj] = __builtin_amdgcn_mfma_f32_16x16x32_bf16(
              afr, bfr[nj], acc[mi][nj], 0, 0, 0);
      }
    }
    __syncthreads();                       // reads done; LDS reusable
  }

  // ---- epilogue: LDS-staged full-line streaming stores ----
  // acc[mi][nj][r] -> Y[row0 + wm*128 + mi*16 + (lane>>4)*4 + r]
  //                    [c0 + wn*64 + nj*16 + lr]
  float bvn[4];
#pragma unroll
  for (int nj = 0; nj < 4; ++nj) {
    const int c = c0 + wn * 64 + nj * 16 + lr;
    bvn[nj] = (c < C_DIM) ? bias[c] : 0.f;
  }

  char* obuf = (char*)&As[0];                    // 32KB of LDS, dead now
  const int cwb = (C_DIM - c0 < 128 ? C_DIM - c0 : 128) * 4; // bytes/row
  const int rwp = wid * 2;                       // wave's row pair base
  const int rsel = lane >> 5;                    // 0/1 within pair
  const int cb  = (lane & 31) * 16;              // byte col within row

#pragma unroll
  for (int slice = 0; slice < 4; ++slice) {      // 64 rows each
    __syncthreads();                             // LDS free for this slice
    if (wm == (slice >> 1)) {
      const int mi0 = (slice & 1) * 4;
#pragma unroll
      for (int mi2 = 0; mi2 < 4; ++mi2) {
#pragma unroll
        for (int nj = 0; nj < 4; ++nj) {
          const int cl = (wn * 64 + nj * 16 + lr) * 4;
#pragma unroll
          for (int r = 0; r < 4; ++r) {
            const int rl = mi2 * 16 + (lane >> 4) * 4 + r;   // 0..63
            *(float*)(obuf + ((rl * 512 + cl) ^ ((rl & 7) << 4))) =
                acc[mi0 + mi2][nj][r] + bvn[nj];
          }
        }
      }
    }
    __syncthreads();                             // slice fully written
    // stream: 8 passes; one wave covers 2 rows x 512B (full 128B lines)
#pragma unroll
    for (int pass = 0; pass < 8; ++pass) {
      const int rl = pass * 8 + rwp + rsel;      // 0..63
      const f32x4 v =
          *(const f32x4*)(obuf + ((rl * 512 + cb) ^ ((rl & 7) << 4)));
      if (cb < cwb) {
        const int64_t m = row0 + slice * 64 + rl;
        f32x4* dst = (f32x4*)((char*)(Y + m * (int64_t)C_DIM) + c0 * 4 + cb);
        __builtin_nontemporal_store(v, dst);
      }
    }
  }
}

// ---------------------------------------------------------------------------
extern "C" void kernel_launch(void* const* d_in, const int* in_sizes, int n_in,
                              void* d_out, int out_size, void* d_ws, size_t ws_size,
                              hipStream_t stream) {
  const float* x = (const float*)d_in[0];
  const float* W = (const float*)d_in[1];
  const float* b = (const float*)d_in[2];
  float* Y = (float*)d_out;

  unsigned short* S  = (unsigned short*)d_ws;            // 50176*512 bf16 = 51.4 MB
  unsigned short* Wb = S + (size_t)M_ROWS * K_DIM;       // 1024*512 bf16  =  1.0 MB

  hipLaunchKernelGGL(lifw_kernel, dim3(LIF_BLOCKS + WCV_BLOCKS), dim3(256), 0,
                     stream, x, S, W, Wb);
  hipLaunchKernelGGL(gemm_kernel, dim3(1600), dim3(256), 0, stream, S, Wb, b, Y);
}

// Round 14
// 94.362 us; speedup vs baseline: 1.2447x; 1.2447x over previous
//
#include <hip/hip_runtime.h>
#include <hip/hip_bf16.h>
#include <stdint.h>

// ---------------------------------------------------------------------------
// Decoder_10110353014984: LIF multistep (T=4) + linear head
//   x: [4,64,196,512] f32, W: [1000,512] f32, b: [1000] f32
//   y: [4,64,196,1000] f32
// R14 = exact R12/R8 restore (measured best, reproduced twice: 94.27/94.47us).
//   R13's 256x128-wave-reuse variant regressed (117us: serialized A-frag
//   stream + VGPR pressure) and is dropped. Structure ledger (on-HW):
//   R2 256^2 phase-barriers 124 | R3 persistent depth-2 149 | R6 256^2
//   barrier-free 126 | R10 256^2 8-phase counted-vmcnt 112 | R13 256x128
//   reuse 87 | R8/R12 128^2 4-blk/CU 66 (gemm). LIF at 86-90% HBM peak.
//   - lifw: LIF -> bf16 spikes (bit-exact) + W f32->bf16 in trailing blocks.
//   - gemm: 128x128 tile, BK=64, 4 waves (2Mx2N), single-buffered 32KB LDS,
//     m97 2-barrier K-loop, 4 blocks/CU; XOR-swizzled global_load_lds
//     staging (0 conflicts); XCD c-panel grouping (FETCH ~45MB); LDS-staged
//     full-line nontemporal streaming epilogue.
// ---------------------------------------------------------------------------

typedef __attribute__((ext_vector_type(8))) short bf16x8;
typedef __attribute__((ext_vector_type(4))) float f32x4;

#define AS1(p) ((const __attribute__((address_space(1))) void*)(p))
#define AS3(p) ((__attribute__((address_space(3))) void*)(p))

static constexpr int     T_STEPS = 4;
static constexpr int64_t ESP     = 6422528;   // B*N*D = 64*196*512
static constexpr int     K_DIM   = 512;
static constexpr int     C_DIM   = 1000;
static constexpr int64_t M_ROWS  = 50176;     // T*B*N

static constexpr int LIF_BLOCKS = 3136;       // 3136*256 thr * 2 quads = ESP/4
static constexpr int WCV_BLOCKS = 512;        // 512*256*4 elem = 1024*512

__device__ __forceinline__ unsigned short f2bf(float f) {
  unsigned int u = __float_as_uint(f);
  u += 0x7FFFu + ((u >> 16) & 1u);            // round-to-nearest-even
  return (unsigned short)(u >> 16);
}

// ---------------------------------------------------------------------------
// Kernel 1: LIF dynamics -> bf16 spikes + W f32->bf16 in trailing blocks.
// LIF bit-exact vs ref: v += (x-v)*0.5f (exact *0.5), spike iff v >= 1.0f,
// hard reset.
// ---------------------------------------------------------------------------
__global__ void lifw_kernel(const float* __restrict__ x,
                            unsigned short* __restrict__ S,
                            const float* __restrict__ W,
                            unsigned short* __restrict__ Wb) {
  const int b = blockIdx.x;
  if (b >= LIF_BLOCKS) {
    const int idx = (b - LIF_BLOCKS) * 256 + threadIdx.x;  // 0..131071
    const int64_t base = (int64_t)idx * 4;
    const int row = (int)(base >> 9);
    ushort4 o;
    if (row < C_DIM) {
      const float4 wv = *(const float4*)(W + base);
      o.x = f2bf(wv.x); o.y = f2bf(wv.y); o.z = f2bf(wv.z); o.w = f2bf(wv.w);
    } else {
      o.x = o.y = o.z = o.w = 0;
    }
    *(ushort4*)(Wb + base) = o;
    return;
  }
  const int64_t tb = (int64_t)b * 256 + threadIdx.x;
#pragma unroll
  for (int it = 0; it < 2; ++it) {
    const int64_t s0 = (tb + (int64_t)it * LIF_BLOCKS * 256) << 2;
    float v[4] = {0.f, 0.f, 0.f, 0.f};
#pragma unroll
    for (int t = 0; t < T_STEPS; ++t) {
      const float4 xt = *(const float4*)(x + (int64_t)t * ESP + s0);
      const float xa[4] = {xt.x, xt.y, xt.z, xt.w};
      ushort4 sp;
      unsigned short* spp = &sp.x;
#pragma unroll
      for (int j = 0; j < 4; ++j) {
        v[j] = v[j] + (xa[j] - v[j]) * 0.5f;   // charge
        const bool fire = (v[j] >= 1.0f);
        spp[j] = fire ? (unsigned short)0x3F80 : (unsigned short)0; // bf16 1/0
        if (fire) v[j] = 0.0f;                 // hard reset
      }
      *(ushort4*)(S + (int64_t)t * ESP + s0) = sp;
    }
  }
}

// ---------------------------------------------------------------------------
// Kernel 2: GEMM  Y[m,c] = sum_d S[m,d] * Wb[c,d] + b[c]
// 128x128 tile, BK=64, 256 threads (4 waves 2Mx2N, wave tile 64x64),
// single-buffered 32KB LDS, 2-barrier K-loop (m97 structure, 4 blocks/CU).
// Grid 3136 = 392 m-tiles x 8 c-panels; XCD grouping: the 8 c-panels of an
// m-tile are consecutive on one XCD (A-tile = 128KB, L2-shared).
// Epilogue: 2 slices of 64 rows staged in LDS, streamed as full 128B lines
// (one wave = 2 rows x 512B per pass), nontemporal.
// ---------------------------------------------------------------------------
__global__ __launch_bounds__(256, 4) void gemm_kernel(
    const unsigned short* __restrict__ S,
    const unsigned short* __restrict__ Wb,
    const float* __restrict__ bias,
    float* __restrict__ Y) {
  __shared__ __attribute__((aligned(16))) unsigned short As[128 * 64];
  __shared__ __attribute__((aligned(16))) unsigned short Bs[128 * 64];

  const int tid  = threadIdx.x;
  const int lane = tid & 63;
  const int wid  = tid >> 6;      // 0..3
  const int wm   = wid >> 1;      // 0..1  (M half: 64 rows)
  const int wn   = wid & 1;       // 0..1  (N half: 64 cols)

  // XCD grouping: bid%8 = XCD (round-robin dispatch). Per XCD: 392 blocks,
  // j>>3 = local m-tile (49 per XCD), j&7 = c-panel -> 8 siblings adjacent.
  const int bid   = blockIdx.x;
  const int xcd   = bid & 7;
  const int j     = bid >> 3;           // 0..391
  const int mtile = xcd * 49 + (j >> 3);
  const int ntile = j & 7;
  const int64_t row0 = (int64_t)mtile * 128;
  const int     c0   = ntile * 128;

  // staging: one issue = 256 thr x 16B = 4KB = 32 rows x 128B. LDS dest is
  // wave-uniform + lane*16 (linear); swizzle on the GLOBAL source column.
  const int srow = lane >> 3;                 // 0..7
  const int skb  = ((lane & 7) ^ srow) << 4;

  const char* Sg = (const char*)S;
  const char* Wg = (const char*)Wb;
  char* Ab = (char*)As;
  char* Bb = (char*)Bs;

  f32x4 acc[4][4] = {};

  const int lr = lane & 15;
  const int lk = (lane >> 4) * 16;

  for (int t = 0; t < 8; ++t) {            // 8 K-tiles of 64
    const int k0 = t * 64;
#pragma unroll
    for (int i = 0; i < 4; ++i) {          // A: 128 rows = 4 issues
      const int rr = i * 32 + wid * 8;     // uniform row base
      __builtin_amdgcn_global_load_lds(
          AS1(Sg + ((row0 + rr + srow) * (int64_t)K_DIM + k0) * 2 + skb),
          AS3(Ab + rr * 128), 16, 0, 0);
    }
#pragma unroll
    for (int i = 0; i < 4; ++i) {          // B: 128 rows = 4 issues
      const int rr = i * 32 + wid * 8;
      __builtin_amdgcn_global_load_lds(
          AS1(Wg + (((int64_t)c0 + rr + srow) * K_DIM + k0) * 2 + skb),
          AS3(Bb + rr * 128), 16, 0, 0);
    }
    __syncthreads();                       // staging complete

#pragma unroll
    for (int half = 0; half < 2; ++half) { // kk slice of BK=64
      const int kb = half * 64 + lk;
      bf16x8 afr[4], bfr[4];
#pragma unroll
      for (int mi = 0; mi < 4; ++mi) {
        const int r = wm * 64 + mi * 16 + lr;
        afr[mi] = *(const bf16x8*)(Ab + r * 128 + (kb ^ ((r & 7) << 4)));
      }
#pragma unroll
      for (int nj = 0; nj < 4; ++nj) {
        const int r = wn * 64 + nj * 16 + lr;
        bfr[nj] = *(const bf16x8*)(Bb + r * 128 + (kb ^ ((r & 7) << 4)));
      }
#pragma unroll
      for (int mi = 0; mi < 4; ++mi)
#pragma unroll
        for (int nj = 0; nj < 4; ++nj)
          acc[mi][nj] = __builtin_amdgcn_mfma_f32_16x16x32_bf16(
              afr[mi], bfr[nj], acc[mi][nj], 0, 0, 0);
    }
    __syncthreads();                       // reads done; LDS reusable
  }

  // ---- epilogue: LDS-staged full-line streaming stores ----
  // acc[mi][nj][r] -> Y[row0 + wm*64 + mi*16 + (lane>>4)*4 + r]
  //                    [c0 + wn*64 + nj*16 + lr]
  float bvn[4];
#pragma unroll
  for (int nj = 0; nj < 4; ++nj) {
    const int c = c0 + wn * 64 + nj * 16 + lr;
    bvn[nj] = (c < C_DIM) ? bias[c] : 0.f;
  }

  char* obuf = (char*)&As[0];                    // 32KB (As+Bs), dead now
  const int cwb = (C_DIM - c0 < 128 ? C_DIM - c0 : 128) * 4; // bytes/row
  const int rwp = wid * 2;                       // wave's row pair base
  const int rsel = lane >> 5;                    // 0/1 within pair
  const int cb  = (lane & 31) * 16;              // byte col within row

#pragma unroll
  for (int slice = 0; slice < 2; ++slice) {      // 64 rows each
    __syncthreads();                             // LDS free for this slice
    if (wm == slice) {
#pragma unroll
      for (int mi = 0; mi < 4; ++mi) {
#pragma unroll
        for (int nj = 0; nj < 4; ++nj) {
          const int cl = (wn * 64 + nj * 16 + lr) * 4;
#pragma unroll
          for (int r = 0; r < 4; ++r) {
            const int rl = mi * 16 + (lane >> 4) * 4 + r;    // 0..63
            *(float*)(obuf + ((rl * 512 + cl) ^ ((rl & 7) << 4))) =
                acc[mi][nj][r] + bvn[nj];
          }
        }
      }
    }
    __syncthreads();                             // slice fully written
    // stream: 8 passes; one wave covers 2 rows x 512B (full 128B lines)
#pragma unroll
    for (int pass = 0; pass < 8; ++pass) {
      const int rl = pass * 8 + rwp + rsel;      // 0..63
      const f32x4 v =
          *(const f32x4*)(obuf + ((rl * 512 + cb) ^ ((rl & 7) << 4)));
      if (cb < cwb) {
        const int64_t m = row0 + slice * 64 + rl;
        f32x4* dst = (f32x4*)((char*)(Y + m * (int64_t)C_DIM) + c0 * 4 + cb);
        __builtin_nontemporal_store(v, dst);
      }
    }
  }
}

// ---------------------------------------------------------------------------
extern "C" void kernel_launch(void* const* d_in, const int* in_sizes, int n_in,
                              void* d_out, int out_size, void* d_ws, size_t ws_size,
                              hipStream_t stream) {
  const float* x = (const float*)d_in[0];
  const float* W = (const float*)d_in[1];
  const float* b = (const float*)d_in[2];
  float* Y = (float*)d_out;

  unsigned short* S  = (unsigned short*)d_ws;            // 50176*512 bf16 = 51.4 MB
  unsigned short* Wb = S + (size_t)M_ROWS * K_DIM;       // 1024*512 bf16  =  1.0 MB

  hipLaunchKernelGGL(lifw_kernel, dim3(LIF_BLOCKS + WCV_BLOCKS), dim3(256), 0,
                     stream, x, S, W, Wb);
  hipLaunchKernelGGL(gemm_kernel, dim3(3136), dim3(256), 0, stream, S, Wb, b, Y);
}